// Round 5
// baseline (103.659 us; speedup 1.0000x reference)
//
#include <hip/hip_runtime.h>

// PCEN: out = (x / (FLOOR + ema(x))^alpha + delta)^(1/root) - delta^(1/root)
// ema: h[t] = s*x[t] + (1-s)*h[t-1], h[-1] = x[0]  (so ema[0] = x[0])
//
// Chunked scan: each thread owns one (b, chunk, c) run of CHUNK outputs,
// warming up the EMA state over WARM prior steps. 0.96^192 ~ 3.9e-4 residual
// influence of the true initial state -> far under the 7.25e-2 threshold.
// CHUNK=64 -> 524288 threads = 8 waves/SIMD (full occupancy); warm re-reads
// are L2/L3 hits since x (134 MB) fits in the 256 MB Infinity Cache.

#define S_COEF 0.04f
#define OMS    0.96f
#define FLOOR_EPS 1e-6f

constexpr int B_DIM = 64;
constexpr int T_DIM = 4096;
constexpr int C_DIM = 128;
constexpr int CHUNK = 64;
constexpr int WARM  = 192;
constexpr int NCHUNK = T_DIM / CHUNK; // 64

__global__ __launch_bounds__(256, 8) void pcen_kernel(
    const float* __restrict__ x,
    const float* __restrict__ alpha,
    const float* __restrict__ delta,
    const float* __restrict__ root,
    float* __restrict__ out) {
  const int tid   = blockIdx.x * 256 + threadIdx.x;
  const int c     = tid & (C_DIM - 1);
  const int rest  = tid >> 7;                // / C_DIM
  const int chunk = rest & (NCHUNK - 1);
  const int b     = rest >> 6;               // / NCHUNK

  // per-channel params
  const float a     = fminf(alpha[c], 1.0f);
  const float d     = delta[c];
  const float r     = fmaxf(root[c], 1.0f);
  const float oor   = 1.0f / r;
  const float droot = __expf(oor * __logf(d));

  const int t0 = chunk * CHUNK;
  const int tw = (t0 >= WARM) ? (t0 - WARM) : 0;  // tw==0 for early chunks (exact)
  const float* __restrict__ xp = x + ((size_t)b * T_DIM + tw) * C_DIM + c;

  // h_prev = x[tw]; warm loop replays the recurrence up to t0-1.
  float h = *xp;
  const int nwarm = t0 - tw;
  #pragma unroll 16
  for (int i = 0; i < nwarm; ++i) {
    const float xv = *xp; xp += C_DIM;
    h = fmaf(OMS, h, S_COEF * xv);
  }

  float* __restrict__ op = out + ((size_t)b * T_DIM + t0) * C_DIM + c;
  #pragma unroll 4
  for (int i = 0; i < CHUNK; ++i) {
    const float xv = *xp; xp += C_DIM;
    h = fmaf(OMS, h, S_COEF * xv);
    const float e     = FLOOR_EPS + h;
    const float scale = __expf(-a * __logf(e));      // (floor+ema)^-alpha
    const float base  = fmaf(xv, scale, d);          // x*(...)^-alpha + delta
    const float o     = __expf(oor * __logf(base)) - droot;
    __builtin_nontemporal_store(o, op);              // keep L3 for the input
    op += C_DIM;
  }
}

extern "C" void kernel_launch(void* const* d_in, const int* in_sizes, int n_in,
                              void* d_out, int out_size, void* d_ws, size_t ws_size,
                              hipStream_t stream) {
  const float* x     = (const float*)d_in[0];
  const float* alpha = (const float*)d_in[1];
  const float* delta = (const float*)d_in[2];
  const float* root  = (const float*)d_in[3];
  float* out = (float*)d_out;

  const int total_threads = B_DIM * NCHUNK * C_DIM; // 524288
  pcen_kernel<<<total_threads / 256, 256, 0, stream>>>(x, alpha, delta, root, out);
}

// Round 7
// 84.240 us; speedup vs baseline: 1.2305x; 1.2305x over previous
//
#include <hip/hip_runtime.h>

// PCEN: out = (x / (FLOOR + ema(x))^alpha + delta)^(1/root) - delta^(1/root)
// ema: h[t] = s*x[t] + (1-s)*h[t-1], h[-1] = x[0]
//
// Exact two-pass chunked scan (no warm-up approximation, no read amplification):
//   EMA over a CHUNK is affine: h_end = A*h_start + B, A = 0.96^CHUNK,
//   B = chunk-local scan with zero init.
//   Pass 1: B[b][chunk][cg] -> d_ws (4 MB), reading x once as float4.
//   Pass 2: fold preceding B's (L2-hot) to get h_start exactly, then re-read
//   the chunk's x (L3-resident: 134 MB < 256 MiB Infinity Cache; output stores
//   are nontemporal so they don't evict x) and emit outputs as float4.
// All global accesses are 16 B/lane (float4) — R1/R5 showed the dword pattern
// pins at ~3.7 TB/s; the 6.3 TB/s ceiling is a float4 number.

#define S_COEF 0.04f
#define OMS    0.96f
#define FLOOR_EPS 1e-6f

constexpr int B_DIM  = 64;
constexpr int T_DIM  = 4096;
constexpr int C_DIM  = 128;
constexpr int CHUNK  = 32;
constexpr int NCHUNK = T_DIM / CHUNK;  // 128
constexpr int CG     = C_DIM / 4;      // 32 float4 channel-groups
constexpr float A_CHUNK = 0.27081920f; // 0.96^32

// native vector type for nontemporal builtins (HIP float4 class is rejected)
typedef float f32x4_t __attribute__((ext_vector_type(4)));

__device__ __forceinline__ void nt_store4(const float4& v, float4* p) {
  f32x4_t tmp;
  tmp.x = v.x; tmp.y = v.y; tmp.z = v.z; tmp.w = v.w;
  __builtin_nontemporal_store(tmp, (f32x4_t*)p);
}

__device__ __forceinline__ float pcen_pt(float xv, float h, float a, float d,
                                         float oor, float droot) {
  const float e     = FLOOR_EPS + h;
  const float scale = __expf(-a * __logf(e));      // (floor+ema)^-alpha
  const float base  = fmaf(xv, scale, d);
  return __expf(oor * __logf(base)) - droot;
}

// ---- Pass 1: per-chunk local EMA tail B ----
__global__ __launch_bounds__(256) void pcen_pass1(
    const float* __restrict__ x, float4* __restrict__ Bws) {
  const int tid   = blockIdx.x * 256 + threadIdx.x;
  const int cg    = tid & (CG - 1);
  const int rest  = tid >> 5;
  const int chunk = rest & (NCHUNK - 1);
  const int b     = rest >> 7;

  const float4* __restrict__ xp =
      (const float4*)(x + ((size_t)b * T_DIM + (size_t)chunk * CHUNK) * C_DIM) + cg;

  float4 p = {0.f, 0.f, 0.f, 0.f};
  #pragma unroll 8
  for (int i = 0; i < CHUNK; ++i) {
    const float4 xv = xp[(size_t)i * CG];
    p.x = fmaf(OMS, p.x, S_COEF * xv.x);
    p.y = fmaf(OMS, p.y, S_COEF * xv.y);
    p.z = fmaf(OMS, p.z, S_COEF * xv.z);
    p.w = fmaf(OMS, p.w, S_COEF * xv.w);
  }
  Bws[tid] = p;  // tid enumerates (b, chunk, cg) exactly
}

// ---- Pass 2: boundary fold + outputs ----
__global__ __launch_bounds__(256) void pcen_pass2(
    const float* __restrict__ x,
    const float* __restrict__ alpha,
    const float* __restrict__ delta,
    const float* __restrict__ root,
    const float4* __restrict__ Bws,
    float* __restrict__ out) {
  const int tid   = blockIdx.x * 256 + threadIdx.x;
  const int cg    = tid & (CG - 1);
  const int rest  = tid >> 5;
  const int chunk = rest & (NCHUNK - 1);
  const int b     = rest >> 7;

  // per-channel params (4 consecutive channels per thread)
  const float4 al = ((const float4*)alpha)[cg];
  const float4 de = ((const float4*)delta)[cg];
  const float4 ro = ((const float4*)root)[cg];
  const float a0 = fminf(al.x, 1.f), a1 = fminf(al.y, 1.f),
              a2 = fminf(al.z, 1.f), a3 = fminf(al.w, 1.f);
  const float o0 = 1.f / fmaxf(ro.x, 1.f), o1 = 1.f / fmaxf(ro.y, 1.f),
              o2 = 1.f / fmaxf(ro.z, 1.f), o3 = 1.f / fmaxf(ro.w, 1.f);
  const float dr0 = __expf(o0 * __logf(de.x)), dr1 = __expf(o1 * __logf(de.y)),
              dr2 = __expf(o2 * __logf(de.z)), dr3 = __expf(o3 * __logf(de.w));

  // boundary state: h_start(chunk) = fold of A*h+B over chunks 0..chunk-1,
  // starting from H[-1] = x[b,0,c]
  const float4* __restrict__ xb = (const float4*)(x + (size_t)b * T_DIM * C_DIM) + cg;
  float4 h = xb[0];
  const float4* __restrict__ Bp = Bws + (size_t)b * NCHUNK * CG + cg;
  int k = 0;
  for (; k + 4 <= chunk; k += 4) {  // group-of-4: batch loads, then fold
    const float4 B0 = Bp[(size_t)(k + 0) * CG];
    const float4 B1 = Bp[(size_t)(k + 1) * CG];
    const float4 B2 = Bp[(size_t)(k + 2) * CG];
    const float4 B3 = Bp[(size_t)(k + 3) * CG];
    h.x = fmaf(A_CHUNK, h.x, B0.x); h.y = fmaf(A_CHUNK, h.y, B0.y);
    h.z = fmaf(A_CHUNK, h.z, B0.z); h.w = fmaf(A_CHUNK, h.w, B0.w);
    h.x = fmaf(A_CHUNK, h.x, B1.x); h.y = fmaf(A_CHUNK, h.y, B1.y);
    h.z = fmaf(A_CHUNK, h.z, B1.z); h.w = fmaf(A_CHUNK, h.w, B1.w);
    h.x = fmaf(A_CHUNK, h.x, B2.x); h.y = fmaf(A_CHUNK, h.y, B2.y);
    h.z = fmaf(A_CHUNK, h.z, B2.z); h.w = fmaf(A_CHUNK, h.w, B2.w);
    h.x = fmaf(A_CHUNK, h.x, B3.x); h.y = fmaf(A_CHUNK, h.y, B3.y);
    h.z = fmaf(A_CHUNK, h.z, B3.z); h.w = fmaf(A_CHUNK, h.w, B3.w);
  }
  for (; k < chunk; ++k) {
    const float4 Bv = Bp[(size_t)k * CG];
    h.x = fmaf(A_CHUNK, h.x, Bv.x); h.y = fmaf(A_CHUNK, h.y, Bv.y);
    h.z = fmaf(A_CHUNK, h.z, Bv.z); h.w = fmaf(A_CHUNK, h.w, Bv.w);
  }

  // main chunk: exact sequential recurrence + epilogue
  const float4* __restrict__ xp = xb + (size_t)chunk * CHUNK * CG;
  float4* __restrict__ op =
      (float4*)(out + ((size_t)b * T_DIM + (size_t)chunk * CHUNK) * C_DIM) + cg;
  #pragma unroll 4
  for (int i = 0; i < CHUNK; ++i) {
    const float4 xv = xp[(size_t)i * CG];
    h.x = fmaf(OMS, h.x, S_COEF * xv.x);
    h.y = fmaf(OMS, h.y, S_COEF * xv.y);
    h.z = fmaf(OMS, h.z, S_COEF * xv.z);
    h.w = fmaf(OMS, h.w, S_COEF * xv.w);
    float4 o;
    o.x = pcen_pt(xv.x, h.x, a0, de.x, o0, dr0);
    o.y = pcen_pt(xv.y, h.y, a1, de.y, o1, dr1);
    o.z = pcen_pt(xv.z, h.z, a2, de.z, o2, dr2);
    o.w = pcen_pt(xv.w, h.w, a3, de.w, o3, dr3);
    nt_store4(o, op + (size_t)i * CG);
  }
}

// ---- Fallback (ws too small): proven R1 warm-up kernel, 72.7 us ----
constexpr int FCHUNK = 256;
constexpr int FWARM  = 256;
constexpr int FNCHUNK = T_DIM / FCHUNK;

__global__ __launch_bounds__(256) void pcen_warm(
    const float* __restrict__ x, const float* __restrict__ alpha,
    const float* __restrict__ delta, const float* __restrict__ root,
    float* __restrict__ out) {
  const int tid   = blockIdx.x * 256 + threadIdx.x;
  const int c     = tid & (C_DIM - 1);
  const int rest  = tid >> 7;
  const int chunk = rest & (FNCHUNK - 1);
  const int b     = rest >> 4;
  const float a     = fminf(alpha[c], 1.0f);
  const float d     = delta[c];
  const float oor   = 1.0f / fmaxf(root[c], 1.0f);
  const float droot = __expf(oor * __logf(d));
  const int t0 = chunk * FCHUNK;
  const int tw = (t0 >= FWARM) ? (t0 - FWARM) : 0;
  const float* __restrict__ xp = x + ((size_t)b * T_DIM + tw) * C_DIM + c;
  float h = *xp;
  const int nwarm = t0 - tw;
  #pragma unroll 8
  for (int i = 0; i < nwarm; ++i) {
    const float xv = *xp; xp += C_DIM;
    h = fmaf(OMS, h, S_COEF * xv);
  }
  float* __restrict__ op = out + ((size_t)b * T_DIM + t0) * C_DIM + c;
  #pragma unroll 4
  for (int i = 0; i < FCHUNK; ++i) {
    const float xv = *xp; xp += C_DIM;
    h = fmaf(OMS, h, S_COEF * xv);
    const float o = pcen_pt(xv, h, a, d, oor, droot);
    __builtin_nontemporal_store(o, op);
    op += C_DIM;
  }
}

extern "C" void kernel_launch(void* const* d_in, const int* in_sizes, int n_in,
                              void* d_out, int out_size, void* d_ws, size_t ws_size,
                              hipStream_t stream) {
  const float* x     = (const float*)d_in[0];
  const float* alpha = (const float*)d_in[1];
  const float* delta = (const float*)d_in[2];
  const float* root  = (const float*)d_in[3];
  float* out = (float*)d_out;

  const size_t ws_need = (size_t)B_DIM * NCHUNK * CG * sizeof(float4); // 4 MB
  if (ws_size >= ws_need) {
    const int threads = B_DIM * NCHUNK * CG;  // 262144
    pcen_pass1<<<threads / 256, 256, 0, stream>>>(x, (float4*)d_ws);
    pcen_pass2<<<threads / 256, 256, 0, stream>>>(x, alpha, delta, root,
                                                  (const float4*)d_ws, out);
  } else {
    const int threads = B_DIM * FNCHUNK * C_DIM;  // 131072
    pcen_warm<<<threads / 256, 256, 0, stream>>>(x, alpha, delta, root, out);
  }
}

// Round 8
// 79.991 us; speedup vs baseline: 1.2959x; 1.0531x over previous
//
#include <hip/hip_runtime.h>
#include <hip/hip_fp16.h>

// PCEN single-pass block-cooperative chunked scan.
//   Block = (b, 512-step segment). Threads (j in [0,8), cg in [0,32)).
//   Phase A: j scans warm sub-chunk [t0-256+32j, +32) zero-init -> Bw[j][cg].
//   Phase B1: j scans main chunk [t0+64j, +64) zero-init -> Bm[j][cg],
//             stashing x as fp16 in registers (full unroll, static idx).
//   barrier; Phase B2: affine fold h = A*h + B (A = 0.96^32 / 0.96^64) from
//   block-boundary init x[t0-256] (residual 0.96^256 ~ 3e-5), then replay
//   the chunk from registers and emit outputs (float4 nontemporal).
// Traffic = 1.5x read (201 MB) + 1x write (134 MB), all 16 B/lane.

#define S_COEF 0.04f
#define OMS    0.96f
#define FLOOR_EPS 1e-6f

constexpr int B_DIM = 64;
constexpr int T_DIM = 4096;
constexpr int C_DIM = 128;
constexpr int CG    = C_DIM / 4;   // 32 float4 channel-groups
constexpr int NJ    = 8;           // chunks per block
constexpr int CHUNK = 64;          // timesteps per thread (main)
constexpr int TB    = NJ * CHUNK;  // 512 timesteps per block
constexpr int WSUB  = 32;          // warm sub-chunk per thread
constexpr int WARM  = NJ * WSUB;   // 256 warm steps per block
constexpr int NSEG  = T_DIM / TB;  // 8 segments
constexpr float A_W = 0.27081927f; // 0.96^32
constexpr float A_M = 0.07334308f; // 0.96^64

typedef float f32x4_t __attribute__((ext_vector_type(4)));

__device__ __forceinline__ void nt_store4(const float4& v, float4* p) {
  f32x4_t tmp;
  tmp.x = v.x; tmp.y = v.y; tmp.z = v.z; tmp.w = v.w;
  __builtin_nontemporal_store(tmp, (f32x4_t*)p);
}

__device__ __forceinline__ float pcen_pt(float xv, float h, float a, float d,
                                         float oor, float droot) {
  const float e     = FLOOR_EPS + h;
  const float scale = __expf(-a * __logf(e));      // (floor+ema)^-alpha
  const float base  = fmaf(xv, scale, d);
  return __expf(oor * __logf(base)) - droot;
}

__global__ __launch_bounds__(256, 2) void pcen_fused(
    const float* __restrict__ x,
    const float* __restrict__ alpha,
    const float* __restrict__ delta,
    const float* __restrict__ root,
    float* __restrict__ out) {
  __shared__ float4 Bw[NJ][CG];
  __shared__ float4 Bm[NJ][CG];

  const int cg  = threadIdx.x & (CG - 1);
  const int j   = threadIdx.x >> 5;          // [0,8)
  const int seg = blockIdx.x & (NSEG - 1);
  const int b   = blockIdx.x >> 3;
  const int t0  = seg * TB;

  const float4* __restrict__ xb = (const float4*)x + (size_t)b * T_DIM * CG + cg;

  // ---- Phase A: warm sub-chunk local EMA tail (skip for seg 0) ----
  if (seg) {
    const float4* __restrict__ xw = xb + (size_t)(t0 - WARM + j * WSUB) * CG;
    float4 p = {0.f, 0.f, 0.f, 0.f};
    #pragma unroll
    for (int i = 0; i < WSUB; ++i) {
      const float4 xv = xw[(size_t)i * CG];
      p.x = fmaf(OMS, p.x, S_COEF * xv.x);
      p.y = fmaf(OMS, p.y, S_COEF * xv.y);
      p.z = fmaf(OMS, p.z, S_COEF * xv.z);
      p.w = fmaf(OMS, p.w, S_COEF * xv.w);
    }
    Bw[j][cg] = p;
  }

  // ---- Phase B1: main chunk local EMA tail + stash x as fp16 in regs ----
  const float4* __restrict__ xm = xb + (size_t)(t0 + j * CHUNK) * CG;
  __half2 xsA[CHUNK];  // channels 0,1 of this thread's float4
  __half2 xsB[CHUNK];  // channels 2,3
  float4 q = {0.f, 0.f, 0.f, 0.f};
  #pragma unroll
  for (int i = 0; i < CHUNK; ++i) {
    const float4 xv = xm[(size_t)i * CG];
    xsA[i] = __floats2half2_rn(xv.x, xv.y);
    xsB[i] = __floats2half2_rn(xv.z, xv.w);
    q.x = fmaf(OMS, q.x, S_COEF * xv.x);
    q.y = fmaf(OMS, q.y, S_COEF * xv.y);
    q.z = fmaf(OMS, q.z, S_COEF * xv.z);
    q.w = fmaf(OMS, q.w, S_COEF * xv.w);
  }
  Bm[j][cg] = q;

  __syncthreads();

  // ---- Phase B2: fold boundaries, replay from registers, emit ----
  // per-channel params (4 consecutive channels)
  const float4 al = ((const float4*)alpha)[cg];
  const float4 de = ((const float4*)delta)[cg];
  const float4 ro = ((const float4*)root)[cg];
  const float a0 = fminf(al.x, 1.f), a1 = fminf(al.y, 1.f),
              a2 = fminf(al.z, 1.f), a3 = fminf(al.w, 1.f);
  const float o0 = 1.f / fmaxf(ro.x, 1.f), o1 = 1.f / fmaxf(ro.y, 1.f),
              o2 = 1.f / fmaxf(ro.z, 1.f), o3 = 1.f / fmaxf(ro.w, 1.f);
  const float dr0 = __expf(o0 * __logf(de.x)), dr1 = __expf(o1 * __logf(de.y)),
              dr2 = __expf(o2 * __logf(de.z)), dr3 = __expf(o3 * __logf(de.w));

  float4 h;
  if (seg) {
    h = xb[(size_t)(t0 - WARM) * CG];        // warm-window init (approx, 3e-5)
    #pragma unroll
    for (int k = 0; k < NJ; ++k) {
      const float4 Bk = Bw[k][cg];
      h.x = fmaf(A_W, h.x, Bk.x); h.y = fmaf(A_W, h.y, Bk.y);
      h.z = fmaf(A_W, h.z, Bk.z); h.w = fmaf(A_W, h.w, Bk.w);
    }
  } else {
    h = xb[0];                               // exact: h[-1] = x[0]
  }
  for (int k = 0; k < j; ++k) {              // exact within-block prefix
    const float4 Bk = Bm[k][cg];
    h.x = fmaf(A_M, h.x, Bk.x); h.y = fmaf(A_M, h.y, Bk.y);
    h.z = fmaf(A_M, h.z, Bk.z); h.w = fmaf(A_M, h.w, Bk.w);
  }

  float4* __restrict__ op =
      (float4*)out + ((size_t)b * T_DIM + t0 + j * CHUNK) * CG + cg;
  #pragma unroll
  for (int i = 0; i < CHUNK; ++i) {
    const float2 lo = __half22float2(xsA[i]);
    const float2 hi = __half22float2(xsB[i]);
    h.x = fmaf(OMS, h.x, S_COEF * lo.x);
    h.y = fmaf(OMS, h.y, S_COEF * lo.y);
    h.z = fmaf(OMS, h.z, S_COEF * hi.x);
    h.w = fmaf(OMS, h.w, S_COEF * hi.y);
    float4 o;
    o.x = pcen_pt(lo.x, h.x, a0, de.x, o0, dr0);
    o.y = pcen_pt(lo.y, h.y, a1, de.y, o1, dr1);
    o.z = pcen_pt(hi.x, h.z, a2, de.z, o2, dr2);
    o.w = pcen_pt(hi.y, h.w, a3, de.w, o3, dr3);
    nt_store4(o, op + (size_t)i * CG);
  }
}

extern "C" void kernel_launch(void* const* d_in, const int* in_sizes, int n_in,
                              void* d_out, int out_size, void* d_ws, size_t ws_size,
                              hipStream_t stream) {
  const float* x     = (const float*)d_in[0];
  const float* alpha = (const float*)d_in[1];
  const float* delta = (const float*)d_in[2];
  const float* root  = (const float*)d_in[3];
  float* out = (float*)d_out;

  const int nblocks = B_DIM * NSEG;  // 512
  pcen_fused<<<nblocks, 256, 0, stream>>>(x, alpha, delta, root, out);
}